// Round 8
// baseline (161.852 us; speedup 1.0000x reference)
//
#include <hip/hip_runtime.h>

// Problem constants (fixed by reference)
#define B_ 8
#define N_ 8192
#define E_ 131072
#define D_ 128
#define M_ (B_ * N_)          // 65536 rows
#define SLOTS 64              // bucket capacity/node; P[Poisson(16)>64]~1e-21
#define NCH 32                // chunks per batch (counting sort)
#define CHE (E_ / NCH)        // 4096 edges per chunk
constexpr float INV_SQRT_N = 0.011048543456039806f;  // 1/sqrt(8192)
constexpr float LN_EPS_C = 1e-5f;

typedef __attribute__((ext_vector_type(8))) short bf16x8;   // 8 bf16 (4 VGPRs)
typedef __attribute__((ext_vector_type(4))) float f32x4;    // MFMA C/D
typedef __attribute__((ext_vector_type(4))) float f32x4v;   // clang vec (NT ld/st)

static __device__ __forceinline__ unsigned short f2bf(float f) {
  unsigned u = __float_as_uint(f);
  u += 0x7fffu + ((u >> 16) & 1u);
  return (unsigned short)(u >> 16);
}
static __device__ __forceinline__ float bflo(unsigned u) {
  return __uint_as_float(u << 16);
}
static __device__ __forceinline__ float bfhi(unsigned u) {
  return __uint_as_float(u & 0xffff0000u);
}
static __device__ __forceinline__ bf16x8 cvt8v(const f32x4v a, const f32x4v b) {
  bf16x8 r;
  r[0] = (short)f2bf(a.x); r[1] = (short)f2bf(a.y);
  r[2] = (short)f2bf(a.z); r[3] = (short)f2bf(a.w);
  r[4] = (short)f2bf(b.x); r[5] = (short)f2bf(b.y);
  r[6] = (short)f2bf(b.z); r[7] = (short)f2bf(b.w);
  return r;
}

// ---------------------------------------------------------------------------
// Pipeline (R8): counting-sort fill (R7) + FEATURE-SPLIT two-pass gather.
//
// R7 post-mortem: all kernels < 42.4us (harness 43us/256MiB re-poison tops
// the profile). The biggest modeled chunk is the gather: 268 MB of random
// 256-B row reads from hb, whose 4 MB/batch working set == one XCD L2 ->
// capacity thrash (~70% hit -> ~25us of scattered HBM misses). This round
// hb is stored as TWO FEATURE PLANES [2][M][64]; the gather runs as two
// sequential passes, each reading 128-B half-rows from a 2 MB/batch plane
// (fits L2 with headroom). Pass A stages x (f32, numerically identical to
// single-pass) + partial LN stats; pass B combines stats and finalizes.
// ---------------------------------------------------------------------------
__global__ __launch_bounds__(256, 2) void gemm_count_kernel(
    const float* __restrict__ X, const float* __restrict__ W,
    const float* __restrict__ bias, const int* __restrict__ eidx,
    unsigned short* __restrict__ histc, unsigned short* __restrict__ rankb,
    unsigned short* __restrict__ hb) {
  __shared__ unsigned hist[N_];   // 32 KB
  if (blockIdx.x < 256) {
    // ---- MFMA GEMM, 256 nodes/block (proven structure) ----
    const int wave = threadIdx.x >> 6;   // 0..3
    const int lane = threadIdx.x & 63;
    const int m16 = lane & 15;
    const int q = lane >> 4;
    const int hf = wave & 1;     // feature half: feats [hf*64, +64) -> plane hf
    const int ng = wave >> 1;    // node group: nodes [ng*128, +128)

    bf16x8 wf[4][4];  // [kt4][t]
#pragma unroll
    for (int kt4 = 0; kt4 < 4; ++kt4) {
#pragma unroll
      for (int tt = 0; tt < 4; ++tt) {
        const float* wr = W + (size_t)(hf * 64 + tt * 16 + m16) * D_ +
                          kt4 * 32 + q * 8;
        wf[kt4][tt] = cvt8v(*(const f32x4v*)wr, *(const f32x4v*)(wr + 4));
      }
    }

    const int bi = blockIdx.x;
    // batch-aligned node swizzle: batch = bi&7 runs on XCD bi%8
    const int nbase0 = (bi & 7) * N_ + (bi >> 3) * 256 + ng * 128;
    unsigned short* __restrict__ hp = hb + (size_t)hf * M_ * 64;  // plane
#pragma unroll 2
    for (int s = 0; s < 8; ++s) {
      const int nbase = nbase0 + s * 16;
      const float* xrow = X + (size_t)(nbase + m16) * D_;

      f32x4 acc[4];
#pragma unroll
      for (int tt = 0; tt < 4; ++tt) acc[tt] = (f32x4){0.f, 0.f, 0.f, 0.f};

#pragma unroll
      for (int kt4 = 0; kt4 < 4; ++kt4) {
        const f32x4v xa = __builtin_nontemporal_load(
            (const f32x4v*)(xrow + kt4 * 32 + q * 8));
        const f32x4v xb = __builtin_nontemporal_load(
            (const f32x4v*)(xrow + kt4 * 32 + q * 8 + 4));
        const bf16x8 xf = cvt8v(xa, xb);
#pragma unroll
        for (int tt = 0; tt < 4; ++tt) {
          acc[tt] = __builtin_amdgcn_mfma_f32_16x16x32_bf16(wf[kt4][tt], xf,
                                                            acc[tt], 0, 0, 0);
        }
      }

      const size_t prow = (size_t)(nbase + m16) * 64;
#pragma unroll
      for (int tt = 0; tt < 4; ++tt) {
        const int f0 = hf * 64 + tt * 16 + q * 4;
        const float4 b4 = *(const float4*)&bias[f0];
        uint2 uu;
        uu.x = (unsigned)f2bf(acc[tt][0] + b4.x) |
               ((unsigned)f2bf(acc[tt][1] + b4.y) << 16);
        uu.y = (unsigned)f2bf(acc[tt][2] + b4.z) |
               ((unsigned)f2bf(acc[tt][3] + b4.w) << 16);
        *(uint2*)(hp + prow + tt * 16 + q * 4) = uu;
      }
    }
  } else {
    // ---- count + rank: block = (batch b, chunk c of 4096 edges) ----
    const int f = blockIdx.x - 256;   // 0..255
    const int b = f & 7;              // XCD-local edge slice
    const int c = f >> 3;             // 0..31
    const int t = threadIdx.x;

#pragma unroll
    for (int i = 0; i < N_ / 256; ++i) hist[t + i * 256] = 0u;
    __syncthreads();

    const int* __restrict__ tgtp = eidx + b * 2 * E_ + E_ + c * CHE;
    unsigned short* __restrict__ rnk = rankb + (size_t)b * E_ + c * CHE;
    // 16 edges/thread; returning dense histogram adds give the rank free.
#pragma unroll
    for (int k = 0; k < 4; ++k) {
      const int4 tv = *(const int4*)(tgtp + t * 16 + k * 4);
      const unsigned r0 = atomicAdd(&hist[tv.x], 1u);
      const unsigned r1 = atomicAdd(&hist[tv.y], 1u);
      const unsigned r2 = atomicAdd(&hist[tv.z], 1u);
      const unsigned r3 = atomicAdd(&hist[tv.w], 1u);
      uint2 rr;
      rr.x = (r0 & 0xffffu) | (r1 << 16);
      rr.y = (r2 & 0xffffu) | (r3 << 16);
      *(uint2*)(rnk + t * 16 + k * 4) = rr;
    }
    __syncthreads();

    // dump counts as ushort pairs (coalesced u32 stores)
    unsigned* dst = (unsigned*)(histc + ((size_t)b * NCH + c) * N_);
#pragma unroll
    for (int i = 0; i < N_ / 512; ++i) {
      const int j = t + i * 256;               // u32 index 0..4095
      const unsigned lo = hist[2 * j];
      const unsigned hi = hist[2 * j + 1];
      dst[j] = (lo & 0xffffu) | (hi << 16);
    }
  }
}

// ---------------------------------------------------------------------------
// prefix: thread = (batch b, node n). Exclusive prefix of the 32 chunk
// counts -> rewrite histc in place as chunk bases; total -> cnt.
// ---------------------------------------------------------------------------
__global__ __launch_bounds__(256, 8) void prefix_kernel(
    unsigned short* __restrict__ histc, int* __restrict__ cnt) {
  const int b = blockIdx.x & 7;
  const int nb = blockIdx.x >> 3;            // 0..31
  const int n = nb * 256 + threadIdx.x;      // 0..8191
  unsigned short* base = histc + (size_t)b * NCH * N_ + n;
  unsigned short v[NCH];
#pragma unroll
  for (int c = 0; c < NCH; ++c) v[c] = base[(size_t)c * N_];
  unsigned run = 0;
#pragma unroll
  for (int c = 0; c < NCH; ++c) {
    const unsigned x = v[c];
    base[(size_t)c * N_] = (unsigned short)run;
    run += x;
  }
  cnt[b * N_ + n] = (int)run;
}

// ---------------------------------------------------------------------------
// place: pure streaming scatter, no LDS, no atomics. 1024 blocks (4/CU),
// 4 edges/thread: read (tgt,src,rank), gather chunk base (16 KB L2-hot),
// slot = base + rank, fire-and-forget 2 B store.
// ---------------------------------------------------------------------------
__global__ __launch_bounds__(256, 8) void place_kernel(
    const int* __restrict__ eidx, const unsigned short* __restrict__ histc,
    const unsigned short* __restrict__ rankb,
    unsigned short* __restrict__ bucket) {
  const int b = blockIdx.x & 7;        // XCD-local
  const int pos = blockIdx.x >> 3;     // 0..127 (1024-edge groups)
  const int c = pos >> 2;              // chunk 0..31
  const int t = threadIdx.x;
  const int e0 = pos * 1024 + t * 4;

  const int* __restrict__ srcp = eidx + b * 2 * E_;
  const int4 tv = *(const int4*)(srcp + E_ + e0);
  const int4 sv = *(const int4*)(srcp + e0);
  const uint2 rr = *(const uint2*)(rankb + (size_t)b * E_ + e0);
  const unsigned short* __restrict__ basep = histc + ((size_t)b * NCH + c) * N_;
  unsigned short* __restrict__ bkt = bucket + (size_t)b * N_ * SLOTS;

  const unsigned p0 = (unsigned)basep[tv.x] + (rr.x & 0xffffu);
  const unsigned p1 = (unsigned)basep[tv.y] + (rr.x >> 16);
  const unsigned p2 = (unsigned)basep[tv.z] + (rr.y & 0xffffu);
  const unsigned p3 = (unsigned)basep[tv.w] + (rr.y >> 16);
  if (p0 < SLOTS) bkt[(size_t)tv.x * SLOTS + p0] = (unsigned short)sv.x;
  if (p1 < SLOTS) bkt[(size_t)tv.y * SLOTS + p1] = (unsigned short)sv.y;
  if (p2 < SLOTS) bkt[(size_t)tv.z * SLOTS + p2] = (unsigned short)sv.z;
  if (p3 < SLOTS) bkt[(size_t)tv.w * SLOTS + p3] = (unsigned short)sv.w;
}

// ---------------------------------------------------------------------------
// gather pass A (plane 0, feats 0..63): 4 rows/wave, 16 lanes/row, lane owns
// 4 feats (uint2 = 8 B/lane -> 128 B per gathered half-row). Stages x (f32,
// exact) + partial LN stats (sum, sumsq over feats 0..63).
// batch = bid&7 matches K1 writers -> plane-0 slice (2 MB/batch) is L2-warm.
// ---------------------------------------------------------------------------
__global__ __launch_bounds__(256, 8) void gather_half0_kernel(
    const unsigned short* __restrict__ hb0,
    const unsigned short* __restrict__ bucket, const int* __restrict__ cnt,
    float* __restrict__ xh, float2* __restrict__ stats) {
  const int bid = blockIdx.x;
  const int batch = bid & 7;
  const int wave = threadIdx.x >> 6;
  const int lane = threadIdx.x & 63;
  const int g = lane >> 4;
  const int c = lane & 15;
  const int r = (bid >> 3) * 16 + wave * 4 + g;
  const int row = batch * N_ + r;

  const uint2* hub2 = (const uint2*)hb0 + (size_t)batch * N_ * 16;

  const int deg = min(cnt[row], SLOTS);
  const uint2 su = *(const uint2*)&bucket[(size_t)row * SLOTS + c * 4];
  const uint2 ur = hub2[r * 16 + c];

  float a[4] = {0.f, 0.f, 0.f, 0.f};
  for (int jb = 0; jb < deg; jb += 8) {
    const int L = jb >> 2;
    const unsigned w0 = (unsigned)__shfl((int)su.x, L, 16);
    const unsigned w1 = (unsigned)__shfl((int)su.y, L, 16);
    const unsigned w2 = (unsigned)__shfl((int)su.x, L + 1, 16);
    const unsigned w3 = (unsigned)__shfl((int)su.y, L + 1, 16);
    const int idx[8] = {(int)(w0 & 0xffff), (int)(w0 >> 16),
                        (int)(w1 & 0xffff), (int)(w1 >> 16),
                        (int)(w2 & 0xffff), (int)(w2 >> 16),
                        (int)(w3 & 0xffff), (int)(w3 >> 16)};
    uint2 v[8];
#pragma unroll
    for (int i = 0; i < 8; ++i) {
      const bool val = (jb + i) < deg;
      uint2 tv = hub2[(val ? idx[i] : 0) * 16 + c];
      if (!val) tv = (uint2){0u, 0u};
      v[i] = tv;
    }
#pragma unroll
    for (int i = 0; i < 8; ++i) {
      a[0] += bflo(v[i].x); a[1] += bfhi(v[i].x);
      a[2] += bflo(v[i].y); a[3] += bfhi(v[i].y);
    }
  }

  float4 x;
  x.x = bflo(ur.x) + a[0] * INV_SQRT_N;
  x.y = bfhi(ur.x) + a[1] * INV_SQRT_N;
  x.z = bflo(ur.y) + a[2] * INV_SQRT_N;
  x.w = bfhi(ur.y) + a[3] * INV_SQRT_N;

  float s0 = x.x + x.y + x.z + x.w;
  float ss = x.x * x.x + x.y * x.y + x.z * x.z + x.w * x.w;
#pragma unroll
  for (int o = 8; o >= 1; o >>= 1) {
    s0 += __shfl_xor(s0, o, 16);
    ss += __shfl_xor(ss, o, 16);
  }

  *(float4*)(xh + (size_t)row * 64 + c * 4) = x;
  if (c == 0) stats[row] = make_float2(s0, ss);
}

// ---------------------------------------------------------------------------
// gather pass B (plane 1, feats 64..127): same gather structure; combines
// pass-A stats, applies LN + ReLU + mask to BOTH halves, writes out.
// ---------------------------------------------------------------------------
__global__ __launch_bounds__(256, 8) void gather_half1_kernel(
    const unsigned short* __restrict__ hb1,
    const unsigned short* __restrict__ bucket, const int* __restrict__ cnt,
    const float* __restrict__ mask, const float* __restrict__ gamma,
    const float* __restrict__ beta, const float* __restrict__ xh,
    const float2* __restrict__ stats, float* __restrict__ out) {
  const int bid = blockIdx.x;
  const int batch = bid & 7;
  const int wave = threadIdx.x >> 6;
  const int lane = threadIdx.x & 63;
  const int g = lane >> 4;
  const int c = lane & 15;
  const int r = (bid >> 3) * 16 + wave * 4 + g;
  const int row = batch * N_ + r;

  const uint2* hub2 = (const uint2*)hb1 + (size_t)batch * N_ * 16;

  const int deg = min(cnt[row], SLOTS);
  const uint2 su = *(const uint2*)&bucket[(size_t)row * SLOTS + c * 4];
  const uint2 ur = hub2[r * 16 + c];
  const float m = mask[row];

  float a[4] = {0.f, 0.f, 0.f, 0.f};
  for (int jb = 0; jb < deg; jb += 8) {
    const int L = jb >> 2;
    const unsigned w0 = (unsigned)__shfl((int)su.x, L, 16);
    const unsigned w1 = (unsigned)__shfl((int)su.y, L, 16);
    const unsigned w2 = (unsigned)__shfl((int)su.x, L + 1, 16);
    const unsigned w3 = (unsigned)__shfl((int)su.y, L + 1, 16);
    const int idx[8] = {(int)(w0 & 0xffff), (int)(w0 >> 16),
                        (int)(w1 & 0xffff), (int)(w1 >> 16),
                        (int)(w2 & 0xffff), (int)(w2 >> 16),
                        (int)(w3 & 0xffff), (int)(w3 >> 16)};
    uint2 v[8];
#pragma unroll
    for (int i = 0; i < 8; ++i) {
      const bool val = (jb + i) < deg;
      uint2 tv = hub2[(val ? idx[i] : 0) * 16 + c];
      if (!val) tv = (uint2){0u, 0u};
      v[i] = tv;
    }
#pragma unroll
    for (int i = 0; i < 8; ++i) {
      a[0] += bflo(v[i].x); a[1] += bfhi(v[i].x);
      a[2] += bflo(v[i].y); a[3] += bfhi(v[i].y);
    }
  }

  float4 x1;
  x1.x = bflo(ur.x) + a[0] * INV_SQRT_N;
  x1.y = bfhi(ur.x) + a[1] * INV_SQRT_N;
  x1.z = bflo(ur.y) + a[2] * INV_SQRT_N;
  x1.w = bfhi(ur.y) + a[3] * INV_SQRT_N;

  float s0 = x1.x + x1.y + x1.z + x1.w;
  float ss = x1.x * x1.x + x1.y * x1.y + x1.z * x1.z + x1.w * x1.w;
#pragma unroll
  for (int o = 8; o >= 1; o >>= 1) {
    s0 += __shfl_xor(s0, o, 16);
    ss += __shfl_xor(ss, o, 16);
  }
  const float2 st = stats[row];
  s0 += st.x;
  ss += st.y;

  const float mu = s0 * (1.f / 128.f);
  float var = ss * (1.f / 128.f) - mu * mu;
  var = var < 0.f ? 0.f : var;
  const float rstd = rsqrtf(var + LN_EPS_C);

  const float4 x0 = *(const float4*)(xh + (size_t)row * 64 + c * 4);
  const float4 g0 = ((const float4*)gamma)[c];
  const float4 g1 = ((const float4*)gamma)[16 + c];
  const float4 b0 = ((const float4*)beta)[c];
  const float4 b1 = ((const float4*)beta)[16 + c];

  f32x4v o0, o1;
  o0.x = (x0.x - mu) * rstd * g0.x + b0.x;
  o0.y = (x0.y - mu) * rstd * g0.y + b0.y;
  o0.z = (x0.z - mu) * rstd * g0.z + b0.z;
  o0.w = (x0.w - mu) * rstd * g0.w + b0.w;
  o1.x = (x1.x - mu) * rstd * g1.x + b1.x;
  o1.y = (x1.y - mu) * rstd * g1.y + b1.y;
  o1.z = (x1.z - mu) * rstd * g1.z + b1.z;
  o1.w = (x1.w - mu) * rstd * g1.w + b1.w;
  o0.x = (o0.x > 0.f ? o0.x : 0.f) * m;
  o0.y = (o0.y > 0.f ? o0.y : 0.f) * m;
  o0.z = (o0.z > 0.f ? o0.z : 0.f) * m;
  o0.w = (o0.w > 0.f ? o0.w : 0.f) * m;
  o1.x = (o1.x > 0.f ? o1.x : 0.f) * m;
  o1.y = (o1.y > 0.f ? o1.y : 0.f) * m;
  o1.z = (o1.z > 0.f ? o1.z : 0.f) * m;
  o1.w = (o1.w > 0.f ? o1.w : 0.f) * m;

  f32x4v* op = (f32x4v*)out + (size_t)row * 32;
  __builtin_nontemporal_store(o0, op + c);        // feats c*4 .. c*4+3
  __builtin_nontemporal_store(o1, op + 16 + c);   // feats 64+c*4 ..
}

// ---------------------------------------------------------------------------
extern "C" void kernel_launch(void* const* d_in, const int* in_sizes, int n_in,
                              void* d_out, int out_size, void* d_ws,
                              size_t ws_size, hipStream_t stream) {
  const float* X = (const float*)d_in[0];     // [B,N,128]
  const int* eidx = (const int*)d_in[1];      // [B,2,E]
  const float* mask = (const float*)d_in[2];  // [B,N]
  const float* W = (const float*)d_in[3];     // [128,128]
  const float* bias = (const float*)d_in[4];  // [128]
  const float* gamma = (const float*)d_in[5];
  const float* beta = (const float*)d_in[6];
  float* out = (float*)d_out;

  // workspace (~43 MB)
  unsigned short* hb = (unsigned short*)d_ws;              // 2 planes, 16 MB
  unsigned short* bucket = hb + (size_t)2 * M_ * 64;       // 8 MB
  int* cnt = (int*)(bucket + (size_t)M_ * SLOTS);          // 256 KB
  unsigned short* rankb = (unsigned short*)(cnt + M_);     // 2 MB ranks
  float* xh = (float*)(rankb + (size_t)B_ * E_);           // 16 MB staged x
  float2* stats = (float2*)(xh + (size_t)M_ * 64);         // 512 KB
  // chunk count/base table (4 MB) overlaid on `out` — consumed by place
  // before gather_half1 overwrites out.
  unsigned short* histc = (unsigned short*)out;            // [8][32][8192]

  gemm_count_kernel<<<512, 256, 0, stream>>>(X, W, bias, eidx, histc, rankb,
                                             hb);
  prefix_kernel<<<256, 256, 0, stream>>>(histc, cnt);
  place_kernel<<<1024, 256, 0, stream>>>(eidx, histc, rankb, bucket);
  gather_half0_kernel<<<M_ / 16, 256, 0, stream>>>(hb, bucket, cnt, xh, stats);
  gather_half1_kernel<<<M_ / 16, 256, 0, stream>>>(hb + (size_t)M_ * 64,
                                                   bucket, cnt, mask, gamma,
                                                   beta, xh, stats, out);
}

// Round 10
// 151.377 us; speedup vs baseline: 1.0692x; 1.0692x over previous
//
#include <hip/hip_runtime.h>

// Problem constants (fixed by reference)
#define B_ 8
#define N_ 8192
#define E_ 131072
#define D_ 128
#define M_ (B_ * N_)          // 65536 rows
#define SLOTS 64              // bucket capacity/node; P[Poisson(16)>64]~1e-21
#define NCH 32                // chunks per batch (counting sort)
#define CHE (E_ / NCH)        // 4096 edges per chunk
constexpr float INV_SQRT_N = 0.011048543456039806f;  // 1/sqrt(8192)
constexpr float LN_EPS_C = 1e-5f;

typedef __attribute__((ext_vector_type(8))) short bf16x8;   // 8 bf16 (4 VGPRs)
typedef __attribute__((ext_vector_type(4))) float f32x4;    // MFMA C/D
typedef __attribute__((ext_vector_type(4))) float f32x4v;   // clang vec (NT ld/st)
typedef __attribute__((ext_vector_type(4))) unsigned u32x4; // 16 B gather load

static __device__ __forceinline__ unsigned short f2bf(float f) {
  unsigned u = __float_as_uint(f);
  u += 0x7fffu + ((u >> 16) & 1u);
  return (unsigned short)(u >> 16);
}
static __device__ __forceinline__ float bflo(unsigned u) {
  return __uint_as_float(u << 16);
}
static __device__ __forceinline__ float bfhi(unsigned u) {
  return __uint_as_float(u & 0xffff0000u);
}
static __device__ __forceinline__ bf16x8 cvt8v(const f32x4v a, const f32x4v b) {
  bf16x8 r;
  r[0] = (short)f2bf(a.x); r[1] = (short)f2bf(a.y);
  r[2] = (short)f2bf(a.z); r[3] = (short)f2bf(a.w);
  r[4] = (short)f2bf(b.x); r[5] = (short)f2bf(b.y);
  r[6] = (short)f2bf(b.z); r[7] = (short)f2bf(b.w);
  return r;
}

// ---------------------------------------------------------------------------
// R10: exact R7 pipeline revert (R9's cooperative fusion failed under graph
// capture — grid-sync abandoned), plus the register-budget fix found in the
// R9 audit: gather_finalize declared launch_bounds(256,8) = 64 VGPR cap but
// its live set is ~70+ regs (v[8]=32 + a[8] + ur + idx[8] + temps) -> the
// compiler was SPILLING inside the hot gather loop since R0. Now (256,4) =
// 128 regs, no spills, still 16 waves/CU. Same fix for prefix (v[32] array).
// place widened to 8 edges/thread (512 blocks).
// ---------------------------------------------------------------------------
__global__ __launch_bounds__(256, 2) void gemm_count_kernel(
    const float* __restrict__ X, const float* __restrict__ W,
    const float* __restrict__ bias, const int* __restrict__ eidx,
    unsigned short* __restrict__ histc, unsigned short* __restrict__ rankb,
    unsigned short* __restrict__ hb) {
  __shared__ unsigned hist[N_];   // 32 KB
  if (blockIdx.x < 256) {
    // ---- MFMA GEMM, 256 nodes/block (proven structure) ----
    const int wave = threadIdx.x >> 6;   // 0..3
    const int lane = threadIdx.x & 63;
    const int m16 = lane & 15;
    const int q = lane >> 4;
    const int hf = wave & 1;     // feature half: feats [hf*64, +64)
    const int ng = wave >> 1;    // node group: nodes [ng*128, +128)

    bf16x8 wf[4][4];  // [kt4][t]
#pragma unroll
    for (int kt4 = 0; kt4 < 4; ++kt4) {
#pragma unroll
      for (int tt = 0; tt < 4; ++tt) {
        const float* wr = W + (size_t)(hf * 64 + tt * 16 + m16) * D_ +
                          kt4 * 32 + q * 8;
        wf[kt4][tt] = cvt8v(*(const f32x4v*)wr, *(const f32x4v*)(wr + 4));
      }
    }

    const int bi = blockIdx.x;
    // batch-aligned node swizzle: batch = bi&7 runs on XCD bi%8
    const int nbase0 = (bi & 7) * N_ + (bi >> 3) * 256 + ng * 128;
#pragma unroll 2
    for (int s = 0; s < 8; ++s) {
      const int nbase = nbase0 + s * 16;
      const float* xrow = X + (size_t)(nbase + m16) * D_;

      f32x4 acc[4];
#pragma unroll
      for (int tt = 0; tt < 4; ++tt) acc[tt] = (f32x4){0.f, 0.f, 0.f, 0.f};

#pragma unroll
      for (int kt4 = 0; kt4 < 4; ++kt4) {
        const f32x4v xa = __builtin_nontemporal_load(
            (const f32x4v*)(xrow + kt4 * 32 + q * 8));
        const f32x4v xb = __builtin_nontemporal_load(
            (const f32x4v*)(xrow + kt4 * 32 + q * 8 + 4));
        const bf16x8 xf = cvt8v(xa, xb);
#pragma unroll
        for (int tt = 0; tt < 4; ++tt) {
          acc[tt] = __builtin_amdgcn_mfma_f32_16x16x32_bf16(wf[kt4][tt], xf,
                                                            acc[tt], 0, 0, 0);
        }
      }

      const size_t orow = (size_t)(nbase + m16) * D_;
#pragma unroll
      for (int tt = 0; tt < 4; ++tt) {
        const int f0 = hf * 64 + tt * 16 + q * 4;
        const float4 b4 = *(const float4*)&bias[f0];
        uint2 uu;
        uu.x = (unsigned)f2bf(acc[tt][0] + b4.x) |
               ((unsigned)f2bf(acc[tt][1] + b4.y) << 16);
        uu.y = (unsigned)f2bf(acc[tt][2] + b4.z) |
               ((unsigned)f2bf(acc[tt][3] + b4.w) << 16);
        *(uint2*)(hb + orow + f0) = uu;
      }
    }
  } else {
    // ---- count + rank: block = (batch b, chunk c of 4096 edges) ----
    const int f = blockIdx.x - 256;   // 0..255
    const int b = f & 7;              // XCD-local edge slice
    const int c = f >> 3;             // 0..31
    const int t = threadIdx.x;

#pragma unroll
    for (int i = 0; i < N_ / 256; ++i) hist[t + i * 256] = 0u;
    __syncthreads();

    const int* __restrict__ tgtp = eidx + b * 2 * E_ + E_ + c * CHE;
    unsigned short* __restrict__ rnk = rankb + (size_t)b * E_ + c * CHE;
    // 16 edges/thread; returning dense histogram adds give the rank free.
#pragma unroll
    for (int k = 0; k < 4; ++k) {
      const int4 tv = *(const int4*)(tgtp + t * 16 + k * 4);
      const unsigned r0 = atomicAdd(&hist[tv.x], 1u);
      const unsigned r1 = atomicAdd(&hist[tv.y], 1u);
      const unsigned r2 = atomicAdd(&hist[tv.z], 1u);
      const unsigned r3 = atomicAdd(&hist[tv.w], 1u);
      uint2 rr;
      rr.x = (r0 & 0xffffu) | (r1 << 16);
      rr.y = (r2 & 0xffffu) | (r3 << 16);
      *(uint2*)(rnk + t * 16 + k * 4) = rr;
    }
    __syncthreads();

    // dump counts as ushort pairs (coalesced u32 stores)
    unsigned* dst = (unsigned*)(histc + ((size_t)b * NCH + c) * N_);
#pragma unroll
    for (int i = 0; i < N_ / 512; ++i) {
      const int j = t + i * 256;               // u32 index 0..4095
      const unsigned lo = hist[2 * j];
      const unsigned hi = hist[2 * j + 1];
      dst[j] = (lo & 0xffffu) | (hi << 16);
    }
  }
}

// ---------------------------------------------------------------------------
// prefix: thread = (batch b, node n). Exclusive prefix of the 32 chunk
// counts -> rewrite histc in place as chunk bases; total -> cnt.
// launch_bounds(256,4): v[32] register array needs >64 VGPRs (no spills).
// ---------------------------------------------------------------------------
__global__ __launch_bounds__(256, 4) void prefix_kernel(
    unsigned short* __restrict__ histc, int* __restrict__ cnt) {
  const int b = blockIdx.x & 7;
  const int nb = blockIdx.x >> 3;            // 0..31
  const int n = nb * 256 + threadIdx.x;      // 0..8191
  unsigned short* base = histc + (size_t)b * NCH * N_ + n;
  unsigned short v[NCH];
#pragma unroll
  for (int c = 0; c < NCH; ++c) v[c] = base[(size_t)c * N_];
  unsigned run = 0;
#pragma unroll
  for (int c = 0; c < NCH; ++c) {
    const unsigned x = v[c];
    base[(size_t)c * N_] = (unsigned short)run;
    run += x;
  }
  cnt[b * N_ + n] = (int)run;
}

// ---------------------------------------------------------------------------
// place: pure streaming scatter, no LDS, no atomics. 512 blocks (2/CU),
// 8 edges/thread: read (tgt,src,rank), gather chunk base (16 KB L2-hot),
// slot = base + rank, fire-and-forget 2 B store.
// ---------------------------------------------------------------------------
__global__ __launch_bounds__(256, 8) void place_kernel(
    const int* __restrict__ eidx, const unsigned short* __restrict__ histc,
    const unsigned short* __restrict__ rankb,
    unsigned short* __restrict__ bucket) {
  const int b = blockIdx.x & 7;        // XCD-local
  const int pos = blockIdx.x >> 3;     // 0..63 (2048-edge groups)
  const int c = pos >> 1;              // chunk 0..31
  const int t = threadIdx.x;
  const int e0 = pos * 2048 + t * 8;

  const int* __restrict__ srcp = eidx + b * 2 * E_;
  const int4 tv0 = *(const int4*)(srcp + E_ + e0);
  const int4 tv1 = *(const int4*)(srcp + E_ + e0 + 4);
  const int4 sv0 = *(const int4*)(srcp + e0);
  const int4 sv1 = *(const int4*)(srcp + e0 + 4);
  const uint4 rr = *(const uint4*)(rankb + (size_t)b * E_ + e0);
  const unsigned short* __restrict__ basep = histc + ((size_t)b * NCH + c) * N_;
  unsigned short* __restrict__ bkt = bucket + (size_t)b * N_ * SLOTS;

  const unsigned p0 = (unsigned)basep[tv0.x] + (rr.x & 0xffffu);
  const unsigned p1 = (unsigned)basep[tv0.y] + (rr.x >> 16);
  const unsigned p2 = (unsigned)basep[tv0.z] + (rr.y & 0xffffu);
  const unsigned p3 = (unsigned)basep[tv0.w] + (rr.y >> 16);
  const unsigned p4 = (unsigned)basep[tv1.x] + (rr.z & 0xffffu);
  const unsigned p5 = (unsigned)basep[tv1.y] + (rr.z >> 16);
  const unsigned p6 = (unsigned)basep[tv1.z] + (rr.w & 0xffffu);
  const unsigned p7 = (unsigned)basep[tv1.w] + (rr.w >> 16);
  if (p0 < SLOTS) bkt[(size_t)tv0.x * SLOTS + p0] = (unsigned short)sv0.x;
  if (p1 < SLOTS) bkt[(size_t)tv0.y * SLOTS + p1] = (unsigned short)sv0.y;
  if (p2 < SLOTS) bkt[(size_t)tv0.z * SLOTS + p2] = (unsigned short)sv0.z;
  if (p3 < SLOTS) bkt[(size_t)tv0.w * SLOTS + p3] = (unsigned short)sv0.w;
  if (p4 < SLOTS) bkt[(size_t)tv1.x * SLOTS + p4] = (unsigned short)sv1.x;
  if (p5 < SLOTS) bkt[(size_t)tv1.y * SLOTS + p5] = (unsigned short)sv1.y;
  if (p6 < SLOTS) bkt[(size_t)tv1.z * SLOTS + p6] = (unsigned short)sv1.z;
  if (p7 < SLOTS) bkt[(size_t)tv1.w * SLOTS + p7] = (unsigned short)sv1.w;
}

// ---------------------------------------------------------------------------
// K2: gather + residual + LN + ReLU + mask (verified 16-lane-row structure).
// 4 rows/wave, 16 lanes/row, lane owns 8 feats (one u32x4 per gathered row).
// launch_bounds(256,4) THIS ROUND: live set ~70+ VGPRs (v[8]=32 + a[8] +
// ur + idx + temps) exceeded the old (256,8)=64-reg cap -> hot-loop spills
// since R0. 128-reg budget removes them; 16 waves/CU remain for latency.
// batch = bid&7 matches K1 writers -> hb/bucket reads are XCD-L2-warm.
// ---------------------------------------------------------------------------
__global__ __launch_bounds__(256, 4) void gather_finalize_kernel(
    const unsigned short* __restrict__ hb, const unsigned short* __restrict__ bucket,
    const int* __restrict__ cnt, const float* __restrict__ mask,
    const float* __restrict__ gamma, const float* __restrict__ beta,
    float* __restrict__ out) {
  const int bid = blockIdx.x;
  const int batch = bid & 7;             // XCD-locality (matches writers)
  const int wave = threadIdx.x >> 6;
  const int lane = threadIdx.x & 63;
  const int g = lane >> 4;               // row within wave's 4
  const int c = lane & 15;               // 16 lanes per row
  const int r = (bid >> 3) * 16 + wave * 4 + g;  // 0..8191 within batch
  const int row = batch * N_ + r;

  const u32x4* hub4 = (const u32x4*)hb + (size_t)batch * N_ * 16;

  // independent early loads
  const int deg = min(cnt[row], SLOTS);
  const uint2 su = *(const uint2*)&bucket[(size_t)row * SLOTS + c * 4];
  const u32x4 ur = hub4[r * 16 + c];
  const float m = mask[row];

  float a[8];
#pragma unroll
  for (int k = 0; k < 8; ++k) a[k] = 0.f;

  for (int jb = 0; jb < deg; jb += 8) {
    const int L = jb >> 2;
    const unsigned w0 = (unsigned)__shfl((int)su.x, L, 16);      // jb, jb+1
    const unsigned w1 = (unsigned)__shfl((int)su.y, L, 16);      // jb+2, jb+3
    const unsigned w2 = (unsigned)__shfl((int)su.x, L + 1, 16);  // jb+4, jb+5
    const unsigned w3 = (unsigned)__shfl((int)su.y, L + 1, 16);  // jb+6, jb+7
    const int idx[8] = {(int)(w0 & 0xffff), (int)(w0 >> 16),
                        (int)(w1 & 0xffff), (int)(w1 >> 16),
                        (int)(w2 & 0xffff), (int)(w2 >> 16),
                        (int)(w3 & 0xffff), (int)(w3 >> 16)};
    u32x4 v[8];
#pragma unroll
    for (int i = 0; i < 8; ++i) {
      const bool val = (jb + i) < deg;
      const int id = val ? idx[i] : 0;
      u32x4 tv = hub4[id * 16 + c];
      if (!val) tv = (u32x4){0u, 0u, 0u, 0u};
      v[i] = tv;
    }
#pragma unroll
    for (int i = 0; i < 8; ++i) {
      a[0] += bflo(v[i].x); a[1] += bfhi(v[i].x);
      a[2] += bflo(v[i].y); a[3] += bfhi(v[i].y);
      a[4] += bflo(v[i].z); a[5] += bfhi(v[i].z);
      a[6] += bflo(v[i].w); a[7] += bfhi(v[i].w);
    }
  }

  float x[8];
  x[0] = bflo(ur.x) + a[0] * INV_SQRT_N;
  x[1] = bfhi(ur.x) + a[1] * INV_SQRT_N;
  x[2] = bflo(ur.y) + a[2] * INV_SQRT_N;
  x[3] = bfhi(ur.y) + a[3] * INV_SQRT_N;
  x[4] = bflo(ur.z) + a[4] * INV_SQRT_N;
  x[5] = bfhi(ur.z) + a[5] * INV_SQRT_N;
  x[6] = bflo(ur.w) + a[6] * INV_SQRT_N;
  x[7] = bfhi(ur.w) + a[7] * INV_SQRT_N;

  float s0 = 0.f, ss = 0.f;
#pragma unroll
  for (int k = 0; k < 8; ++k) {
    s0 += x[k];
    ss += x[k] * x[k];
  }
#pragma unroll
  for (int o = 8; o >= 1; o >>= 1) {
    s0 += __shfl_xor(s0, o, 16);
    ss += __shfl_xor(ss, o, 16);
  }
  const float mu = s0 * (1.f / 128.f);
  float var = ss * (1.f / 128.f) - mu * mu;
  var = var < 0.f ? 0.f : var;
  const float rstd = rsqrtf(var + LN_EPS_C);

  const f32x4v g0 = *((const f32x4v*)gamma + c * 2);
  const f32x4v g1 = *((const f32x4v*)gamma + c * 2 + 1);
  const f32x4v b0 = *((const f32x4v*)beta + c * 2);
  const f32x4v b1 = *((const f32x4v*)beta + c * 2 + 1);

  f32x4v o0, o1;
  o0.x = (x[0] - mu) * rstd * g0.x + b0.x;
  o0.y = (x[1] - mu) * rstd * g0.y + b0.y;
  o0.z = (x[2] - mu) * rstd * g0.z + b0.z;
  o0.w = (x[3] - mu) * rstd * g0.w + b0.w;
  o1.x = (x[4] - mu) * rstd * g1.x + b1.x;
  o1.y = (x[5] - mu) * rstd * g1.y + b1.y;
  o1.z = (x[6] - mu) * rstd * g1.z + b1.z;
  o1.w = (x[7] - mu) * rstd * g1.w + b1.w;
  o0.x = (o0.x > 0.f ? o0.x : 0.f) * m;
  o0.y = (o0.y > 0.f ? o0.y : 0.f) * m;
  o0.z = (o0.z > 0.f ? o0.z : 0.f) * m;
  o0.w = (o0.w > 0.f ? o0.w : 0.f) * m;
  o1.x = (o1.x > 0.f ? o1.x : 0.f) * m;
  o1.y = (o1.y > 0.f ? o1.y : 0.f) * m;
  o1.z = (o1.z > 0.f ? o1.z : 0.f) * m;
  o1.w = (o1.w > 0.f ? o1.w : 0.f) * m;

  f32x4v* op = (f32x4v*)out + (size_t)row * 32 + c * 2;
  __builtin_nontemporal_store(o0, op);
  __builtin_nontemporal_store(o1, op + 1);
}

// ---------------------------------------------------------------------------
extern "C" void kernel_launch(void* const* d_in, const int* in_sizes, int n_in,
                              void* d_out, int out_size, void* d_ws,
                              size_t ws_size, hipStream_t stream) {
  const float* X = (const float*)d_in[0];     // [B,N,128]
  const int* eidx = (const int*)d_in[1];      // [B,2,E]
  const float* mask = (const float*)d_in[2];  // [B,N]
  const float* W = (const float*)d_in[3];     // [128,128]
  const float* bias = (const float*)d_in[4];  // [128]
  const float* gamma = (const float*)d_in[5];
  const float* beta = (const float*)d_in[6];
  float* out = (float*)d_out;

  // workspace (~26.5 MB)
  unsigned short* hb = (unsigned short*)d_ws;             // 16 MB bf16
  unsigned short* bucket = hb + (size_t)M_ * D_;          // 8 MB (M_*64 ushort)
  int* cnt = (int*)(bucket + (size_t)M_ * SLOTS);         // 256 KB
  unsigned short* rankb = (unsigned short*)(cnt + M_);    // 2 MB ranks
  // chunk count/base table (4 MB) overlaid on `out` — consumed by place
  // before gather overwrites out.
  unsigned short* histc = (unsigned short*)out;           // [8][32][8192]

  gemm_count_kernel<<<512, 256, 0, stream>>>(X, W, bias, eidx, histc, rankb,
                                             hb);
  prefix_kernel<<<256, 256, 0, stream>>>(histc, cnt);
  place_kernel<<<512, 256, 0, stream>>>(eidx, histc, rankb, bucket);
  gather_finalize_kernel<<<M_ / 16, 256, 0, stream>>>(hb, bucket, cnt, mask,
                                                      gamma, beta, out);
}